// Round 1
// baseline (27425.320 us; speedup 1.0000x reference)
//
#include <hip/hip_runtime.h>
#include <stdint.h>

typedef _Float16 f16;
typedef _Float16 h8  __attribute__((ext_vector_type(8)));
typedef _Float16 h4v __attribute__((ext_vector_type(4)));
typedef _Float16 h2v __attribute__((ext_vector_type(2)));
typedef float    fx4 __attribute__((ext_vector_type(4)));

constexpr int HDIM   = 512;
constexpr int SEQT   = 256;
constexpr int NBATCH = 32;
constexpr int NCOL   = 4096;   // 2 dirs * 2048 gate rows

// ---- ws layout (bytes) ----
constexpr size_t OFF_E    = 0;            // 16 f32
constexpr size_t OFF_BIAS = 0x1000;       // 2 layers * 4096 f32
constexpr size_t OFF_WHH  = 0x10000;      // 4 * 2048*512 f16 (layer*2+dir)
constexpr size_t OFF_WIH0 = 0x00900000;   // 4096*512  f16
constexpr size_t OFF_WIH1 = 0x00D00000;   // 4096*1024 f16
constexpr size_t OFF_XF16 = 0x01500000;   // 8192*512  f16
constexpr size_t OFF_HS0  = 0x01D00000;   // 8192*1024 f16 (layer0 output)
constexpr size_t OFF_XP   = 0x02D00000;   // 8192*4096 f16
constexpr size_t OFF_HBUF = 0x06D00000;   // 2*2*32*512 f16 (double-buffered h)
constexpr size_t OFF_CTR  = 0x06D20000;   // 2 layers * [2][256][16] u32 = 64KB
constexpr size_t WS_NEED  = 0x06D30000;   // ~109.2 MB

__device__ __forceinline__ float sigmoidf_(float x) { return 1.0f / (1.0f + __expf(-x)); }
__device__ __forceinline__ float tanhf_(float x) {
  float e2 = __expf(2.0f * x);
  return (e2 - 1.0f) / (e2 + 1.0f);
}
__device__ __forceinline__ float dot8(h8 a, h8 b, float acc) {
#if __has_builtin(__builtin_amdgcn_fdot2)
  union U { h8 v; h2v p[4]; };
  U ua, ub; ua.v = a; ub.v = b;
  acc = __builtin_amdgcn_fdot2(ua.p[0], ub.p[0], acc, false);
  acc = __builtin_amdgcn_fdot2(ua.p[1], ub.p[1], acc, false);
  acc = __builtin_amdgcn_fdot2(ua.p[2], ub.p[2], acc, false);
  acc = __builtin_amdgcn_fdot2(ua.p[3], ub.p[3], acc, false);
#else
  #pragma unroll
  for (int i = 0; i < 8; i++) acc += (float)a[i] * (float)b[i];
#endif
  return acc;
}

// ---- e = renorm(emb_table[domain_id]) ----
__global__ void k_e(const float* __restrict__ emb, const int* __restrict__ dom,
                    float* __restrict__ e_out) {
  int lane = threadIdx.x;
  float v = 0.f;
  int d = *dom;
  if (lane < 16) v = emb[d * 16 + lane];
  float s = v * v;
  s += __shfl_xor(s, 1); s += __shfl_xor(s, 2);
  s += __shfl_xor(s, 4); s += __shfl_xor(s, 8);
  float n = sqrtf(s);
  float scale = fminf(1.0f, 1.0f / fmaxf(n, 1e-7f));
  if (lane < 16) e_out[lane] = v * scale;
}

// ---- Whh generation -> f16, 4 tensors of 2048x512, index = layer*2+dir ----
__global__ void k_gen_whh(const float* __restrict__ s0, const float* __restrict__ s1,
                          const float* __restrict__ s2, const float* __restrict__ s3,
                          const float* __restrict__ e, f16* __restrict__ out) {
  int idx = blockIdx.x * 256 + threadIdx.x;      // 4 * 1048576 total
  int t = idx >> 20;
  int rem = idx & 1048575;                        // g*512 + k
  const float* src = (t == 0) ? s0 : (t == 1) ? s1 : (t == 2) ? s2 : s3;
  const float4* w = (const float4*)(src + (size_t)rem * 16);
  float acc = 0.f;
  #pragma unroll
  for (int q = 0; q < 4; q++) {
    float4 wv = w[q];
    acc += wv.x * e[q*4+0] + wv.y * e[q*4+1] + wv.z * e[q*4+2] + wv.w * e[q*4+3];
  }
  out[idx] = (f16)acc;
}

// ---- Wih generation -> f16 rows n = dir*2048+g, cols K (ksh = log2 K) ----
__global__ void k_gen_wih(const float* __restrict__ sf, const float* __restrict__ sr,
                          const float* __restrict__ e, f16* __restrict__ out, int ksh) {
  int idx = blockIdx.x * 256 + threadIdx.x;      // 4096 * K total
  int n = idx >> ksh;
  int k = idx & ((1 << ksh) - 1);
  int dir = n >> 11;
  int g = n & 2047;
  const float* src = dir ? sr : sf;
  const float4* w = (const float4*)(src + ((size_t)(g << ksh) + k) * 16);
  float acc = 0.f;
  #pragma unroll
  for (int q = 0; q < 4; q++) {
    float4 wv = w[q];
    acc += wv.x * e[q*4+0] + wv.y * e[q*4+1] + wv.z * e[q*4+2] + wv.w * e[q*4+3];
  }
  out[idx] = (f16)acc;
}

// ---- bias generation: out[layer*4096 + dir*2048 + g] = (b_ih+b_hh)·e ----
__global__ void k_gen_bias(const float* bi0, const float* bh0, const float* bi0r, const float* bh0r,
                           const float* bi1, const float* bh1, const float* bi1r, const float* bh1r,
                           const float* __restrict__ e, float* __restrict__ out) {
  int idx = blockIdx.x * 256 + threadIdx.x;      // 8192
  int layer = idx >> 12;
  int dir = (idx >> 11) & 1;
  int g = idx & 2047;
  const float* a; const float* b;
  if (layer == 0) { a = dir ? bi0r : bi0; b = dir ? bh0r : bh0; }
  else            { a = dir ? bi1r : bi1; b = dir ? bh1r : bh1; }
  float acc = 0.f;
  #pragma unroll
  for (int m = 0; m < 16; m++) acc += (a[g*16 + m] + b[g*16 + m]) * e[m];
  out[idx] = acc;
}

// ---- fp32 -> fp16 cast (by float4) ----
__global__ void k_cast(const float* __restrict__ x, f16* __restrict__ out, int n4) {
  int i = blockIdx.x * 256 + threadIdx.x;
  if (i < n4) {
    float4 v = ((const float4*)x)[i];
    h4v o; o[0] = (f16)v.x; o[1] = (f16)v.y; o[2] = (f16)v.z; o[3] = (f16)v.w;
    *(h4v*)(out + (size_t)i * 4) = o;
  }
}

// ---- GEMM: C[m][n] = sum_k A[m][k]*B[n][k] + bias[n], A:(8192,K) B:(4096,K) f16, C f16 ----
__launch_bounds__(256, 2)
__global__ void k_gemm(const f16* __restrict__ A, const f16* __restrict__ B,
                       const float* __restrict__ bias, f16* __restrict__ C, int K) {
  __shared__ f16 Al[128 * 64];
  __shared__ f16 Bl[128 * 64];
  const int tid = threadIdx.x;
  const int m0 = blockIdx.x * 128;
  const int n0 = blockIdx.y * 128;
  const int lane = tid & 63, wave = tid >> 6;
  const int wm = (wave >> 1) * 64, wn = (wave & 1) * 64;
  const int quad = lane >> 4, m16 = lane & 15;
  const int r_row = tid >> 3;
  const int r_c8 = tid & 7;
  fx4 acc[4][4] = {};
  for (int kb = 0; kb < K; kb += 64) {
    h8 ra[4], rb[4];
    #pragma unroll
    for (int r = 0; r < 4; r++) {
      int row = r * 32 + r_row;
      int c8 = r_c8 ^ (row & 7);
      ra[r] = *(const h8*)(A + (size_t)(m0 + row) * K + kb + c8 * 8);
      rb[r] = *(const h8*)(B + (size_t)(n0 + row) * K + kb + c8 * 8);
    }
    __syncthreads();
    #pragma unroll
    for (int r = 0; r < 4; r++) {
      *(h8*)(Al + (r * 256 + tid) * 8) = ra[r];
      *(h8*)(Bl + (r * 256 + tid) * 8) = rb[r];
    }
    __syncthreads();
    #pragma unroll
    for (int kk = 0; kk < 2; kk++) {
      h8 af[4], bf[4];
      #pragma unroll
      for (int i = 0; i < 4; i++) {
        int arow = wm + i * 16 + m16;
        int slot = (kk * 4 + quad) ^ (arow & 7);
        af[i] = *(const h8*)(Al + arow * 64 + slot * 8);
      }
      #pragma unroll
      for (int j = 0; j < 4; j++) {
        int brow = wn + j * 16 + m16;
        int slot = (kk * 4 + quad) ^ (brow & 7);
        bf[j] = *(const h8*)(Bl + brow * 64 + slot * 8);
      }
      #pragma unroll
      for (int i = 0; i < 4; i++)
        #pragma unroll
        for (int j = 0; j < 4; j++)
          acc[i][j] = __builtin_amdgcn_mfma_f32_16x16x32_f16(af[i], bf[j], acc[i][j], 0, 0, 0);
    }
  }
  // epilogue: D[m = quad*4+reg][n = m16]
  #pragma unroll
  for (int j = 0; j < 4; j++) {
    int n = n0 + wn + j * 16 + m16;
    float bv = bias[n];
    #pragma unroll
    for (int i = 0; i < 4; i++) {
      int mbase = m0 + wm + i * 16 + quad * 4;
      #pragma unroll
      for (int rr = 0; rr < 4; rr++)
        C[(size_t)(mbase + rr) * NCOL + n] = (f16)(acc[i][j][rr] + bv);
    }
  }
}

// ---- persistent recurrence kernel: one launch per layer, grid 256 (co-resident) ----
// wg < 128: fwd, wg >= 128: bwd.  wg owns j-block [4w,4w+4) -> 16 gate rows.
__launch_bounds__(256, 1)
__global__ void k_rec(const f16* __restrict__ Whh,   // [2][2048*512] this layer, dir-major
                      const f16* __restrict__ Xp,    // [8192][4096] f16 (includes bias)
                      f16* __restrict__ hbuf,        // [2][2][32][512] f16
                      unsigned int* __restrict__ ctr,// [2][256][16] u32 (this layer)
                      f16* __restrict__ out16,       // hs0 (layer0) or null
                      float* __restrict__ out32)     // d_out (layer1) or null
{
  __shared__ f16 wl[16 * 512];     // rotated storage
  __shared__ f16 hl[32 * 520];     // rotated, padded stride 520
  const int wg = blockIdx.x;
  const int dir = wg >> 7;
  const int w = wg & 127;
  const int tid = threadIdx.x;
  const int wave = tid >> 6;
  const int lane = tid & 63;
  const int bgl = lane & 3;
  const int ks = (lane >> 2) & 15;         // kseg: lane bits 2..5
  const int bg = (wave << 2) | bgl;        // 0..15 (pair of batches)
  const bool clane = (ks == 0);
  const f16* whhd = Whh + ((size_t)dir << 20);

  // load this wg's 16 gate rows into LDS, granule-rotated: slot = (g + kseg) & 3
  #pragma unroll
  for (int i = 0; i < 4; i++) {
    int gl = i * 256 + tid;                 // 1024 granules (16 rows * 64)
    int r = gl >> 6;
    int g6 = gl & 63;
    int kseg = g6 >> 2, g = g6 & 3;
    int slot = (g + kseg) & 3;
    int grow = (r >> 2) * 512 + w * 4 + (r & 3);   // gate*512 + j
    h8 v = *(const h8*)(whhd + (size_t)grow * 512 + g6 * 8);
    *(h8*)(wl + r * 512 + kseg * 32 + slot * 8) = v;
  }
  float c_st[4][2] = {};                    // persistent cell state on clanes
  __syncthreads();

  for (int step = 0; step < SEQT; step++) {
    const int treal = dir ? (SEQT - 1 - step) : step;
    // prefetch Xp (independent of h -> issued before the spin)
    h4v xp[4][2];
    if (clane) {
      #pragma unroll
      for (int bi = 0; bi < 2; bi++) {
        int b = bg * 2 + bi;
        const f16* base = Xp + ((size_t)(b * SEQT + treal)) * NCOL + dir * 2048 + w * 4;
        #pragma unroll
        for (int gate = 0; gate < 4; gate++)
          xp[gate][bi] = *(const h4v*)(base + gate * 512);
      }
    }
    float red[16][2];
    if (step > 0) {
      if (tid == 0) {
        unsigned int* c16 = ctr + ((dir * SEQT + (step - 1)) << 4);
        long it = 0;
        while (true) {
          unsigned int s = 0;
          #pragma unroll
          for (int q = 0; q < 16; q++)
            s += __hip_atomic_load(&c16[q], __ATOMIC_RELAXED, __HIP_MEMORY_SCOPE_AGENT);
          if (s >= 128u) break;
          if (++it > 200000) break;        // safety bound against deadlock
          __builtin_amdgcn_s_sleep(1);
        }
      }
      __syncthreads();
      __threadfence();                      // acquire: invalidate L1/L2 before h loads
      // cooperative load h[32][512] f16 -> LDS (rotated)
      const f16* hsrc = hbuf + (((size_t)(step & 1) * 2 + dir) * 32) * 512;
      #pragma unroll
      for (int i = 0; i < 8; i++) {
        int gl = i * 256 + tid;             // 2048 granules
        int b = gl >> 6, g6 = gl & 63;
        int kseg = g6 >> 2, g = g6 & 3;
        int slot = (g + kseg) & 3;
        h8 v = *(const h8*)(hsrc + (size_t)b * 512 + g6 * 8);
        *(h8*)(hl + b * 520 + kseg * 32 + slot * 8) = v;
      }
      __syncthreads();
      // pull this thread's h slice: 2 batches x 4 granules
      h8 hr[2][4];
      #pragma unroll
      for (int bi = 0; bi < 2; bi++) {
        int b = bg * 2 + bi;
        #pragma unroll
        for (int s4 = 0; s4 < 4; s4++)
          hr[bi][s4] = *(const h8*)(hl + b * 520 + ks * 32 + s4 * 8);
      }
      float acc[16][2];
      #pragma unroll
      for (int r = 0; r < 16; r++) { acc[r][0] = 0.f; acc[r][1] = 0.f; }
      #pragma unroll
      for (int r = 0; r < 16; r++) {
        #pragma unroll
        for (int s4 = 0; s4 < 4; s4++) {
          h8 wv = *(const h8*)(wl + r * 512 + ks * 32 + s4 * 8);  // broadcast read
          acc[r][0] = dot8(wv, hr[0][s4], acc[r][0]);
          acc[r][1] = dot8(wv, hr[1][s4], acc[r][1]);
        }
      }
      // full k-reduction in-wave: ks occupies lane bits 2..5
      #pragma unroll
      for (int r = 0; r < 16; r++) {
        #pragma unroll
        for (int bi = 0; bi < 2; bi++) {
          float v = acc[r][bi];
          v += __shfl_xor(v, 4);
          v += __shfl_xor(v, 8);
          v += __shfl_xor(v, 16);
          v += __shfl_xor(v, 32);
          red[r][bi] = v;
        }
      }
    } else {
      #pragma unroll
      for (int r = 0; r < 16; r++) { red[r][0] = 0.f; red[r][1] = 0.f; }
    }
    // gate math + state update on clanes (b = bg*2+bi, 4 j's each)
    if (clane) {
      #pragma unroll
      for (int bi = 0; bi < 2; bi++) {
        int b = bg * 2 + bi;
        h4v hq;
        fx4 ho;
        #pragma unroll
        for (int jq = 0; jq < 4; jq++) {
          float gi = red[0 + jq][bi]  + (float)xp[0][bi][jq];
          float gf = red[4 + jq][bi]  + (float)xp[1][bi][jq];
          float gg = red[8 + jq][bi]  + (float)xp[2][bi][jq];
          float go = red[12 + jq][bi] + (float)xp[3][bi][jq];
          float ig = sigmoidf_(gi);
          float fg = sigmoidf_(gf);
          float og = sigmoidf_(go);
          float tg = tanhf_(gg);
          float cc = fg * c_st[jq][bi] + ig * tg;
          c_st[jq][bi] = cc;
          float hv = og * tanhf_(cc);
          hq[jq] = (f16)hv;
          ho[jq] = hv;
        }
        *(h4v*)(hbuf + ((((size_t)(step + 1) & 1) * 2 + dir) * 32 + b) * 512 + w * 4) = hq;
        if (out16)
          *(h4v*)(out16 + ((size_t)(b * SEQT + treal)) * 1024 + dir * 512 + w * 4) = hq;
        if (out32)
          *(fx4*)(out32 + ((size_t)(b * SEQT + treal)) * 1024 + dir * 512 + w * 4) = ho;
      }
    }
    __threadfence();                        // release: drain h stores to agent scope
    __syncthreads();
    if (tid == 0 && step < SEQT - 1)
      atomicAdd(&ctr[((dir * SEQT + step) << 4) + (w >> 3)], 1u);
  }
}

extern "C" void kernel_launch(void* const* d_in, const int* in_sizes, int n_in,
                              void* d_out, int out_size, void* d_ws, size_t ws_size,
                              hipStream_t stream) {
  const float* x       = (const float*)d_in[0];
  const float* emb     = (const float*)d_in[1];
  const float* wih_l0  = (const float*)d_in[2];
  const float* whh_l0  = (const float*)d_in[3];
  const float* bih_l0  = (const float*)d_in[4];
  const float* bhh_l0  = (const float*)d_in[5];
  const float* wih_l0r = (const float*)d_in[6];
  const float* whh_l0r = (const float*)d_in[7];
  const float* bih_l0r = (const float*)d_in[8];
  const float* bhh_l0r = (const float*)d_in[9];
  const float* wih_l1  = (const float*)d_in[10];
  const float* whh_l1  = (const float*)d_in[11];
  const float* bih_l1  = (const float*)d_in[12];
  const float* bhh_l1  = (const float*)d_in[13];
  const float* wih_l1r = (const float*)d_in[14];
  const float* whh_l1r = (const float*)d_in[15];
  const float* bih_l1r = (const float*)d_in[16];
  const float* bhh_l1r = (const float*)d_in[17];
  const int*   dom     = (const int*)d_in[18];
  float* out = (float*)d_out;
  char* ws = (char*)d_ws;
  if (ws_size < WS_NEED) return;   // insufficient scratch; bench will flag mismatch

  float* e_vec = (float*)(ws + OFF_E);
  float* biasb = (float*)(ws + OFF_BIAS);
  f16* whh16 = (f16*)(ws + OFF_WHH);
  f16* wih0  = (f16*)(ws + OFF_WIH0);
  f16* wih1  = (f16*)(ws + OFF_WIH1);
  f16* xf16  = (f16*)(ws + OFF_XF16);
  f16* hs0   = (f16*)(ws + OFF_HS0);
  f16* xp    = (f16*)(ws + OFF_XP);
  f16* hbuf  = (f16*)(ws + OFF_HBUF);
  unsigned int* ctr = (unsigned int*)(ws + OFF_CTR);

  hipMemsetAsync(ws + OFF_CTR, 0, 0x10000, stream);
  k_e<<<1, 64, 0, stream>>>(emb, dom, e_vec);
  k_gen_whh<<<16384, 256, 0, stream>>>(whh_l0, whh_l0r, whh_l1, whh_l1r, e_vec, whh16);
  k_gen_wih<<<8192, 256, 0, stream>>>(wih_l0, wih_l0r, e_vec, wih0, 9);
  k_gen_wih<<<16384, 256, 0, stream>>>(wih_l1, wih_l1r, e_vec, wih1, 10);
  k_gen_bias<<<32, 256, 0, stream>>>(bih_l0, bhh_l0, bih_l0r, bhh_l0r,
                                     bih_l1, bhh_l1, bih_l1r, bhh_l1r, e_vec, biasb);
  k_cast<<<4096, 256, 0, stream>>>(x, xf16, 1048576);
  // layer 0
  k_gemm<<<dim3(64, 32), 256, 0, stream>>>(xf16, wih0, biasb, xp, 512);
  k_rec<<<256, 256, 0, stream>>>(whh16, xp, hbuf, ctr, hs0, nullptr);
  // layer 1
  k_gemm<<<dim3(64, 32), 256, 0, stream>>>(hs0, wih1, biasb + 4096, xp, 1024);
  k_rec<<<256, 256, 0, stream>>>(whh16 + ((size_t)2 << 20), xp, hbuf, ctr + 8192,
                                 nullptr, out);
}